// Round 10
// baseline (133.805 us; speedup 1.0000x reference)
//
#include <hip/hip_runtime.h>

#define BINS 10
#define NTHREADS 256
#define GRID 2048

// Packed per-thread-per-bin word: bits [31:25] = count, bits [24:0] = sum of pt
// in 2^-18 fixed point. Max 64 pairs/thread/bin < 127; 64*2^18 < 2^25: no overflow.
#define CNT_SHIFT 25
#define SUM_SCALE 262144.0f        // 2^18
#define SUM_INV   (1.0f / 262144.0f)
#define SUM_MASK  0x01FFFFFFu

// b = min((int)(g*10.0f), 9) reproduces searchsorted(edges, g, 'right')-1 exactly
// for all f32 g in [0,1]: verified at every edge f32(k/10) and its predecessor
// (incl. RNE ties at 10*E3, 10*E6, 10*pred(E7)). g<=1.0 always (pred in [0,1)).
__device__ __forceinline__ void do_row(float p0, float p1, int t,
                                       unsigned int* __restrict__ col)
{
    const bool  is0 = (t == 0);
    const float g0  = is0 ? (1.0f - p0) : p0;   // |p0 - onehot0| (p0 >= 0)
    const float g1  = is0 ? p1 : (1.0f - p1);   // |p1 - onehot1|
    const float pt  = is0 ? p0 : p1;            // pred[i, target[i]]
    const int b0 = min((int)(g0 * 10.0f), 9);
    const int b1 = min((int)(g1 * 10.0f), 9);
    const unsigned int inc =
        (1u << CNT_SHIFT) + (unsigned int)__fmaf_rn(pt, SUM_SCALE, 0.5f);
    atomicAdd(&col[b0 * NTHREADS], inc);   // private column: no contention
    atomicAdd(&col[b1 * NTHREADS], inc);
}

// One 8-row group: 4 float4 of pred + 2 int4 of target (96B in flight per lane).
#define DO_GROUP(A, B, C, D, T0, T1)            \
    do {                                        \
        do_row((A).x, (A).y, (T0).x, col);      \
        do_row((A).z, (A).w, (T0).y, col);      \
        do_row((B).x, (B).y, (T0).z, col);      \
        do_row((B).z, (B).w, (T0).w, col);      \
        do_row((C).x, (C).y, (T1).x, col);      \
        do_row((C).z, (C).w, (T1).y, col);      \
        do_row((D).x, (D).y, (T1).z, col);      \
        do_row((D).z, (D).w, (T1).w, col);      \
    } while (0)

// Single fused kernel. Election fixed vs round 9: ticket is memset to 0 each
// call (4-byte memsetAsync), so old == GRID-1 IS the true last arrival (round
// 9's mod-trick elected the 1366th arrival from the poisoned base -> it read
// 682 unwritten partial rows). Cross-XCD visibility per Guideline 16: partials
// move via agent-scope atomics (per-XCD L2s are not coherent; plain stores +
// threadfence are not guaranteed).
__global__ __launch_bounds__(NTHREADS, 8) void ghm_fused_kernel(
    const float* __restrict__ pred,
    const int* __restrict__ target,
    int N,
    unsigned int* __restrict__ ticket,   // zeroed by memsetAsync each call
    int* __restrict__ part_cnt,          // [BINS][GRID]
    float* __restrict__ part_sum,        // [BINS][GRID]
    float* __restrict__ out)
{
    __shared__ unsigned int s_hist[BINS][NTHREADS];   // [bin][thread]: bank = tid%32
    __shared__ int   s_c[4][BINS];
    __shared__ float s_s[4][BINS];
    __shared__ unsigned int s_elect;

    const int tid = threadIdx.x;
    unsigned int* col = &s_hist[0][tid];

    #pragma unroll
    for (int b = 0; b < BINS; ++b) col[b * NTHREADS] = 0u;
    // no sync needed: each thread touches only its own column until the reduce

    const int gtid   = blockIdx.x * blockDim.x + tid;
    const int stride = gridDim.x * blockDim.x;
    const int n8     = N >> 3;            // 8-row groups
    const int iters  = n8 / stride;       // uniform trip count for ALL threads

    const float4* __restrict__ pred4 = (const float4*)pred;  // 2 rows per float4
    const int4*   __restrict__ tgt4  = (const int4*)target;  // 4 targets per int4

    // Round-7 loop verbatim (measured best 44.55us): depth-1 prefetch with
    // sched_barrier(0) keeping the loads issued above the compute.
    float4 cA, cB, cC, cD;
    int4   cT0, cT1;
    int i = gtid;
    if (iters > 0) {
        cA  = pred4[4 * i + 0];
        cB  = pred4[4 * i + 1];
        cC  = pred4[4 * i + 2];
        cD  = pred4[4 * i + 3];
        cT0 = tgt4[2 * i + 0];
        cT1 = tgt4[2 * i + 1];
    }
    for (int k = 1; k < iters; ++k) {
        const int j = i + stride;         // in-bounds by construction (k < iters)
        const float4 nA  = pred4[4 * j + 0];
        const float4 nB  = pred4[4 * j + 1];
        const float4 nC  = pred4[4 * j + 2];
        const float4 nD  = pred4[4 * j + 3];
        const int4   nT0 = tgt4[2 * j + 0];
        const int4   nT1 = tgt4[2 * j + 1];
        __builtin_amdgcn_sched_barrier(0);   // loads stay issued above compute
        DO_GROUP(cA, cB, cC, cD, cT0, cT1);  // overlaps the 6 loads above
        cA = nA; cB = nB; cC = nC; cD = nD; cT0 = nT0; cT1 = nT1;
        i = j;
    }
    if (iters > 0) DO_GROUP(cA, cB, cC, cD, cT0, cT1);

    // leftover 8-row groups (none when n8 % stride == 0)
    {
        const int r = iters * stride + gtid;
        if (r < n8) {
            const float4 A  = pred4[4 * r + 0];
            const float4 B  = pred4[4 * r + 1];
            const float4 C  = pred4[4 * r + 2];
            const float4 D  = pred4[4 * r + 3];
            const int4   T0 = tgt4[2 * r + 0];
            const int4   T1 = tgt4[2 * r + 1];
            DO_GROUP(A, B, C, D, T0, T1);
        }
    }
    // leftover rows (N % 8)
    {
        const int row = n8 * 8 + gtid;
        if (row < N)
            do_row(pred[2 * row], pred[2 * row + 1], target[row], col);
    }

    __syncthreads();   // drain LDS atomics before the cross-thread reduce

    // unpack own column
    int   cnt[BINS];
    float sum[BINS];
    #pragma unroll
    for (int b = 0; b < BINS; ++b) {
        const unsigned int w = col[b * NTHREADS];
        cnt[b] = (int)(w >> CNT_SHIFT);
        sum[b] = (float)(w & SUM_MASK) * SUM_INV;
    }

    // wave shfl reduce -> cross-wave LDS -> agent-scope per-block partial stores
    const int lane = tid & 63;
    const int wave = tid >> 6;
    #pragma unroll
    for (int b = 0; b < BINS; ++b) {
        int   c = cnt[b];
        float s = sum[b];
        #pragma unroll
        for (int off = 32; off > 0; off >>= 1) {
            c += __shfl_down(c, off);
            s += __shfl_down(s, off);
        }
        if (lane == 0) { s_c[wave][b] = c; s_s[wave][b] = s; }
    }
    __syncthreads();
    if (tid < BINS) {
        const int   c = s_c[0][tid] + s_c[1][tid] + s_c[2][tid] + s_c[3][tid];
        const float s = s_s[0][tid] + s_s[1][tid] + s_s[2][tid] + s_s[3][tid];
        // agent scope: write through to the coherence point (cross-XCD visible)
        __hip_atomic_store(&part_cnt[tid * GRID + blockIdx.x], c,
                           __ATOMIC_RELAXED, __HIP_MEMORY_SCOPE_AGENT);
        __hip_atomic_store(&part_sum[tid * GRID + blockIdx.x], s,
                           __ATOMIC_RELAXED, __HIP_MEMORY_SCOPE_AGENT);
    }

    // ---- election: true last arrival (counter starts at 0 each call)
    __syncthreads();                     // all partial stores vmcnt-drained
    if (tid == 0) {
        const unsigned int old = __hip_atomic_fetch_add(
            ticket, 1u, __ATOMIC_ACQ_REL, __HIP_MEMORY_SCOPE_AGENT);
        s_elect = (old == GRID - 1u) ? 1u : 0u;
    }
    __syncthreads();
    if (s_elect == 0u) return;

    // ---- elected (last) block: all 2048 partial rows are written & released.
    int   rc[BINS];
    float rs[BINS];
    #pragma unroll
    for (int b = 0; b < BINS; ++b) { rc[b] = 0; rs[b] = 0.0f; }
    for (int e = tid; e < GRID; e += NTHREADS) {   // coalesced dword loads
        #pragma unroll
        for (int b = 0; b < BINS; ++b) {
            rc[b] += __hip_atomic_load(&part_cnt[b * GRID + e],
                                       __ATOMIC_RELAXED, __HIP_MEMORY_SCOPE_AGENT);
            rs[b] += __hip_atomic_load(&part_sum[b * GRID + e],
                                       __ATOMIC_RELAXED, __HIP_MEMORY_SCOPE_AGENT);
        }
    }
    #pragma unroll
    for (int b = 0; b < BINS; ++b) {
        int   cc = rc[b];
        float ss = rs[b];
        #pragma unroll
        for (int off = 32; off > 0; off >>= 1) {
            cc += __shfl_down(cc, off);
            ss += __shfl_down(ss, off);
        }
        if (lane == 0) { s_c[wave][b] = cc; s_s[wave][b] = ss; }
    }
    __syncthreads();
    if (tid == 0) {
        // result = -(1/(2*n_nonempty)) * sum_b S_b / cnt_b   (tot cancels exactly)
        int nne = 0;
        float acc = 0.0f;
        #pragma unroll
        for (int b = 0; b < BINS; ++b) {
            const int   cc = s_c[0][b] + s_c[1][b] + s_c[2][b] + s_c[3][b];
            const float ss = s_s[0][b] + s_s[1][b] + s_s[2][b] + s_s[3][b];
            if (cc > 0) { nne++; acc += ss / (float)cc; }
        }
        out[0] = (nne > 0) ? (-acc / (2.0f * (float)nne)) : 0.0f;
    }
}

extern "C" void kernel_launch(void* const* d_in, const int* in_sizes, int n_in,
                              void* d_out, int out_size, void* d_ws, size_t ws_size,
                              hipStream_t stream) {
    const float* pred   = (const float*)d_in[0];
    const int*   target = (const int*)d_in[1];
    const int N = in_sizes[1];  // rows

    unsigned int* ticket   = (unsigned int*)d_ws;
    int*          part_cnt = (int*)((char*)d_ws + 64);             // 16B-aligned
    float*        part_sum = (float*)((char*)d_ws + 64 + BINS * GRID * sizeof(int));

    hipMemsetAsync(ticket, 0, sizeof(unsigned int), stream);       // election base
    ghm_fused_kernel<<<GRID, NTHREADS, 0, stream>>>(pred, target, N, ticket,
                                                    part_cnt, part_sum, (float*)d_out);
}

// Round 11
// 44.710 us; speedup vs baseline: 2.9927x; 2.9927x over previous
//
#include <hip/hip_runtime.h>

#define BINS 10
#define NTHREADS 256
#define GRID 2048

// Packed per-thread-per-bin word: bits [31:25] = count, bits [24:0] = sum of pt
// in 2^-18 fixed point. Max 64 pairs/thread/bin < 127; 64*2^18 < 2^25: no overflow.
#define CNT_SHIFT 25
#define SUM_SCALE 262144.0f        // 2^18
#define SUM_INV   (1.0f / 262144.0f)
#define SUM_MASK  0x01FFFFFFu

// b = min((int)(g*10.0f), 9) reproduces searchsorted(edges, g, 'right')-1 exactly
// for all f32 g in [0,1]: verified at every edge f32(k/10) and its predecessor
// (incl. RNE ties at 10*E3, 10*E6, 10*pred(E7)). g<=1.0 always (pred in [0,1)).
__device__ __forceinline__ void do_row(float p0, float p1, int t,
                                       unsigned int* __restrict__ col)
{
    const bool  is0 = (t == 0);
    const float g0  = is0 ? (1.0f - p0) : p0;   // |p0 - onehot0| (p0 >= 0)
    const float g1  = is0 ? p1 : (1.0f - p1);   // |p1 - onehot1|
    const float pt  = is0 ? p0 : p1;            // pred[i, target[i]]
    const int b0 = min((int)(g0 * 10.0f), 9);
    const int b1 = min((int)(g1 * 10.0f), 9);
    const unsigned int inc =
        (1u << CNT_SHIFT) + (unsigned int)__fmaf_rn(pt, SUM_SCALE, 0.5f);
    atomicAdd(&col[b0 * NTHREADS], inc);   // private column: no contention
    atomicAdd(&col[b1 * NTHREADS], inc);
}

// One 8-row group: 4 float4 of pred + 2 int4 of target (96B in flight per lane).
#define DO_GROUP(A, B, C, D, T0, T1)            \
    do {                                        \
        do_row((A).x, (A).y, (T0).x, col);      \
        do_row((A).z, (A).w, (T0).y, col);      \
        do_row((B).x, (B).y, (T0).z, col);      \
        do_row((B).z, (B).w, (T0).w, col);      \
        do_row((C).x, (C).y, (T1).x, col);      \
        do_row((C).z, (C).w, (T1).y, col);      \
        do_row((D).x, (D).y, (T1).z, col);      \
        do_row((D).z, (D).w, (T1).w, col);      \
    } while (0)

// Two-kernel structure ON PURPOSE (round 10 post-mortem): single-kernel fusion
// needs agent-scope release/acquire for cross-XCD partials, which compiles to
// buffer_wbl2 + buffer_inv per block -> 2048 L2 flushes destroyed streaming
// locality (44.6 -> 133.8us). The dispatch boundary gives ordering for free.
__global__ __launch_bounds__(NTHREADS, 8) void ghm_hist_kernel(
    const float* __restrict__ pred,
    const int* __restrict__ target,
    int N,
    int* __restrict__ part_cnt,      // [BINS][GRID]  (transposed for stage-2 coalescing)
    float* __restrict__ part_sum)    // [BINS][GRID]
{
    __shared__ unsigned int s_hist[BINS][NTHREADS];   // [bin][thread]: bank = tid%32
    __shared__ int   s_c[4][BINS];
    __shared__ float s_s[4][BINS];

    const int tid = threadIdx.x;
    unsigned int* col = &s_hist[0][tid];

    #pragma unroll
    for (int b = 0; b < BINS; ++b) col[b * NTHREADS] = 0u;
    // no sync needed: each thread touches only its own column until the reduce

    const int gtid   = blockIdx.x * blockDim.x + tid;
    const int stride = gridDim.x * blockDim.x;
    const int n8     = N >> 3;            // 8-row groups
    const int iters  = n8 / stride;       // uniform trip count for ALL threads

    const float4* __restrict__ pred4 = (const float4*)pred;  // 2 rows per float4
    const int4*   __restrict__ tgt4  = (const int4*)target;  // 4 targets per int4

    // Depth-1 software pipeline over 8-row groups with sched_barrier(0) pinning
    // the prefetch loads above the compute (best measured variant, 44.55us).
    float4 cA, cB, cC, cD;
    int4   cT0, cT1;
    int i = gtid;
    if (iters > 0) {
        cA  = pred4[4 * i + 0];
        cB  = pred4[4 * i + 1];
        cC  = pred4[4 * i + 2];
        cD  = pred4[4 * i + 3];
        cT0 = tgt4[2 * i + 0];
        cT1 = tgt4[2 * i + 1];
    }
    for (int k = 1; k < iters; ++k) {
        const int j = i + stride;         // in-bounds by construction (k < iters)
        const float4 nA  = pred4[4 * j + 0];
        const float4 nB  = pred4[4 * j + 1];
        const float4 nC  = pred4[4 * j + 2];
        const float4 nD  = pred4[4 * j + 3];
        const int4   nT0 = tgt4[2 * j + 0];
        const int4   nT1 = tgt4[2 * j + 1];
        __builtin_amdgcn_sched_barrier(0);   // loads stay issued above compute
        DO_GROUP(cA, cB, cC, cD, cT0, cT1);  // overlaps the 6 loads above
        cA = nA; cB = nB; cC = nC; cD = nD; cT0 = nT0; cT1 = nT1;
        i = j;
    }
    if (iters > 0) DO_GROUP(cA, cB, cC, cD, cT0, cT1);

    // leftover 8-row groups (none when n8 % stride == 0)
    {
        const int r = iters * stride + gtid;
        if (r < n8) {
            const float4 A  = pred4[4 * r + 0];
            const float4 B  = pred4[4 * r + 1];
            const float4 C  = pred4[4 * r + 2];
            const float4 D  = pred4[4 * r + 3];
            const int4   T0 = tgt4[2 * r + 0];
            const int4   T1 = tgt4[2 * r + 1];
            DO_GROUP(A, B, C, D, T0, T1);
        }
    }
    // leftover rows (N % 8)
    {
        const int row = n8 * 8 + gtid;
        if (row < N)
            do_row(pred[2 * row], pred[2 * row + 1], target[row], col);
    }

    __syncthreads();   // drain LDS atomics before the cross-thread reduce

    // unpack own column
    int   cnt[BINS];
    float sum[BINS];
    #pragma unroll
    for (int b = 0; b < BINS; ++b) {
        const unsigned int w = col[b * NTHREADS];
        cnt[b] = (int)(w >> CNT_SHIFT);
        sum[b] = (float)(w & SUM_MASK) * SUM_INV;
    }

    // wave shfl reduce -> cross-wave LDS -> plain per-block partial stores
    // (no global atomics: 2048 x 20 same-address RMWs was the ~60us tail in r1-4)
    const int lane = tid & 63;
    const int wave = tid >> 6;
    #pragma unroll
    for (int b = 0; b < BINS; ++b) {
        int   c = cnt[b];
        float s = sum[b];
        #pragma unroll
        for (int off = 32; off > 0; off >>= 1) {
            c += __shfl_down(c, off);
            s += __shfl_down(s, off);
        }
        if (lane == 0) { s_c[wave][b] = c; s_s[wave][b] = s; }
    }
    __syncthreads();
    if (tid < BINS) {
        const int   c = s_c[0][tid] + s_c[1][tid] + s_c[2][tid] + s_c[3][tid];
        const float s = s_s[0][tid] + s_s[1][tid] + s_s[2][tid] + s_s[3][tid];
        part_cnt[tid * GRID + blockIdx.x] = c;
        part_sum[tid * GRID + blockIdx.x] = s;
    }
}

// Stage 2: one 512-thread block reduces [BINS][GRID] partials, emits the scalar.
// result = -(1/(2*n_nonempty)) * sum_b S_b / cnt_b   (tot cancels exactly)
__global__ __launch_bounds__(512) void ghm_reduce_kernel(
    const int* __restrict__ part_cnt,
    const float* __restrict__ part_sum,
    float* __restrict__ out)
{
    __shared__ int   s_c[8][BINS];
    __shared__ float s_s[8][BINS];
    const int tid = threadIdx.x;

    const int4*   __restrict__ pc4 = (const int4*)part_cnt;     // 512 int4 per bin
    const float4* __restrict__ ps4 = (const float4*)part_sum;

    int   c[BINS];
    float s[BINS];
    #pragma unroll
    for (int b = 0; b < BINS; ++b) {
        const int4   vc = pc4[b * (GRID / 4) + tid];
        const float4 vs = ps4[b * (GRID / 4) + tid];
        c[b] = vc.x + vc.y + vc.z + vc.w;
        s[b] = vs.x + vs.y + vs.z + vs.w;
    }

    const int lane = tid & 63;
    const int wave = tid >> 6;
    #pragma unroll
    for (int b = 0; b < BINS; ++b) {
        int   cc = c[b];
        float ss = s[b];
        #pragma unroll
        for (int off = 32; off > 0; off >>= 1) {
            cc += __shfl_down(cc, off);
            ss += __shfl_down(ss, off);
        }
        if (lane == 0) { s_c[wave][b] = cc; s_s[wave][b] = ss; }
    }
    __syncthreads();
    if (tid == 0) {
        int nne = 0;
        float acc = 0.0f;
        #pragma unroll
        for (int b = 0; b < BINS; ++b) {
            int   cc = 0;
            float ss = 0.0f;
            #pragma unroll
            for (int w = 0; w < 8; ++w) { cc += s_c[w][b]; ss += s_s[w][b]; }
            if (cc > 0) { nne++; acc += ss / (float)cc; }
        }
        out[0] = (nne > 0) ? (-acc / (2.0f * (float)nne)) : 0.0f;
    }
}

extern "C" void kernel_launch(void* const* d_in, const int* in_sizes, int n_in,
                              void* d_out, int out_size, void* d_ws, size_t ws_size,
                              hipStream_t stream) {
    const float* pred   = (const float*)d_in[0];
    const int*   target = (const int*)d_in[1];
    const int N = in_sizes[1];  // rows

    int*   part_cnt = (int*)d_ws;                                  // BINS*GRID ints
    float* part_sum = (float*)((char*)d_ws + BINS * GRID * sizeof(int));

    ghm_hist_kernel<<<GRID, NTHREADS, 0, stream>>>(pred, target, N, part_cnt, part_sum);
    ghm_reduce_kernel<<<1, 512, 0, stream>>>(part_cnt, part_sum, (float*)d_out);
}